// Round 4
// baseline (622.907 us; speedup 1.0000x reference)
//
#include <hip/hip_runtime.h>
#include <math.h>

// Fixed shapes: b_edges (64,1,512,512) f32, sobel (64,2,512,512) f32
// BASE=256, PY_SIZES=[256,64]
// One wave == one "group" g = b*64 + R: output rows 4R..4R+3 of image b,
// lane X owns the 4 px (cols 4X..4X+3) x 4 rows = one level-1 cell (R, X).
// Everything (predicates, sobel values, 4x4 pool, compaction ranks) lives in
// registers; global row offsets via ticket-ordered decoupled lookback.

typedef unsigned long long u64;
#define OFFSET1 4194304
#define NGROUPS 4096

// state word: flag(2) | incl1/agg1 (20 bits, <<24) | incl0/agg0 (24 bits)
__device__ __forceinline__ u64 pack_state(unsigned flag, unsigned v0, unsigned v1) {
    return ((u64)flag << 62) | ((u64)v1 << 24) | (u64)v0;
}

__global__ __launch_bounds__(256) void zero_kernel(u64* __restrict__ state,
                                                   int* __restrict__ aux) {
    int t = blockIdx.x * 256 + threadIdx.x;
    if (t < NGROUPS) state[t] = 0ull;
    if (t < 8) aux[t] = 0;   // [0]=ticket [1]=total0 [2]=total1 [3]=done
}

__global__ __launch_bounds__(512) void fused_kernel(const float* __restrict__ E,
                                                    const float* __restrict__ S,
                                                    u64* __restrict__ state,
                                                    int* __restrict__ aux,
                                                    float* __restrict__ out, int N) {
    int tid = threadIdx.x;
    int lane = tid & 63;

    // per-wave ticket -> group id (monotonic start order => lookback can't deadlock)
    int g;
    if (lane == 0) g = atomicAdd(&aux[0], 1);
    g = __shfl(g, 0, 64);
    int b = g >> 6, R = g & 63;
    int X = lane;

    // align-corners 512->256: pos(i) = i*511/255 (exact f32), lo(i) = 2i.
    // (i=255 -> w=1.0, bit-identical to reference's lo=hi=511 form.)
    float wx[4], cwx[4];
    #pragma unroll
    for (int j = 0; j < 4; ++j) {
        int xi = 4 * X + j;
        wx[j] = (float)(xi * 511) / 255.0f - (float)(8 * X + 2 * j);
        cwx[j] = 1.0f - wx[j];
    }

    // ---------------- pass 1: edge predicates (reads E only) ----------------
    unsigned pred = 0;          // bit (4r+j) = px (row r, col 4X+j) active
    int rowb[4];                // active count in rows < r (wave-uniform)
    int rc = 0;
    #pragma unroll
    for (int r = 0; r < 4; ++r) {
        int y = 4 * R + r, ly = 2 * y;
        float wy = (float)(y * 511) / 255.0f - (float)ly;
        float cwy = 1.0f - wy;
        const float* Ep = E + b * 262144 + ly * 512 + 8 * X;
        float4 eA = *(const float4*)Ep;
        float4 eB = *(const float4*)(Ep + 4);
        float4 eC = *(const float4*)(Ep + 512);
        float4 eD = *(const float4*)(Ep + 516);
        float e0 = (eA.x*cwy + eC.x*wy)*cwx[0] + (eA.y*cwy + eC.y*wy)*wx[0];
        float e1 = (eA.z*cwy + eC.z*wy)*cwx[1] + (eA.w*cwy + eC.w*wy)*wx[1];
        float e2 = (eB.x*cwy + eD.x*wy)*cwx[2] + (eB.y*cwy + eD.y*wy)*wx[2];
        float e3 = (eB.z*cwy + eD.z*wy)*cwx[3] + (eB.w*cwy + eD.w*wy)*wx[3];
        pred |= (e0 != 0.0f ? 1u : 0u) << (4*r+0);
        pred |= (e1 != 0.0f ? 1u : 0u) << (4*r+1);
        pred |= (e2 != 0.0f ? 1u : 0u) << (4*r+2);
        pred |= (e3 != 0.0f ? 1u : 0u) << (4*r+3);
        u64 b0 = __ballot(e0 != 0.0f);
        u64 b1 = __ballot(e1 != 0.0f);
        u64 b2 = __ballot(e2 != 0.0f);
        u64 b3 = __ballot(e3 != 0.0f);
        rowb[r] = rc;
        rc += __popcll(b0) + __popcll(b1) + __popcll(b2) + __popcll(b3);
    }
    u64 m1 = __ballot(pred != 0);   // level-1 cell mask (bit = X)
    int c1 = __popcll(m1);

    if (lane == 0) {
        atomicAdd(&aux[1], rc);     // global N0
        atomicAdd(&aux[2], c1);
        __hip_atomic_store(&state[g], pack_state(1u, (unsigned)rc, (unsigned)c1),
                           __ATOMIC_RELEASE, __HIP_MEMORY_SCOPE_AGENT);
        __hip_atomic_fetch_add(&aux[3], 1, __ATOMIC_RELEASE, __HIP_MEMORY_SCOPE_AGENT);
    }

    // ---------------- decoupled lookback: exclusive prefix over [0, g) ------
    int excl0 = 0, excl1 = 0;
    if (g > 0) {
        int base = g;
        int guard = 0;
        for (;;) {
            int window = base < 64 ? base : 64;
            int idx = base - 1 - lane;           // lane 0 = nearest predecessor
            u64 s = 0;
            if (lane < window)
                s = __hip_atomic_load(&state[idx], __ATOMIC_ACQUIRE,
                                      __HIP_MEMORY_SCOPE_AGENT);
            unsigned flag = (unsigned)(s >> 62);
            u64 inclm  = __ballot(lane < window && flag == 2u);
            u64 validm = __ballot(lane < window && flag >= 1u);
            int first_incl = inclm ? (__ffsll((unsigned long long)inclm) - 1) : 64;
            int need = first_incl < window ? first_incl : window;
            u64 needm = need >= 64 ? ~0ull : ((1ull << need) - 1ull);
            if ((validm & needm) == needm) {
                int take = (lane < need) || (lane == first_incl && first_incl < window);
                int v0 = take ? (int)(s & 0xFFFFFF) : 0;
                int v1 = take ? (int)((s >> 24) & 0xFFFFF) : 0;
                #pragma unroll
                for (int d = 1; d < 64; d <<= 1) {
                    v0 += __shfl_xor(v0, d, 64);
                    v1 += __shfl_xor(v1, d, 64);
                }
                excl0 += v0; excl1 += v1;
                if (first_incl < window) break;  // hit an inclusive -> done
                base -= window;                  // window was all aggregates
                if (base == 0) break;
            } else {
                __builtin_amdgcn_s_sleep(1);
                if (++guard > (1 << 22)) break;  // safety valve (never expected)
            }
        }
    }
    if (lane == 0)
        __hip_atomic_store(&state[g],
                           pack_state(2u, (unsigned)(excl0 + rc), (unsigned)(excl1 + c1)),
                           __ATOMIC_RELEASE, __HIP_MEMORY_SCOPE_AGENT);

    // ---------------- pass 2: sobel values + L0 row writes ------------------
    const float* Sp = S + (size_t)(b * 2) * 262144;
    float acc0 = 0.0f, acc1 = 0.0f;
    #pragma unroll
    for (int r = 0; r < 4; ++r) {
        int y = 4 * R + r, ly = 2 * y;
        float wy = (float)(y * 511) / 255.0f - (float)ly;
        float cwy = 1.0f - wy;
        const float* Sa = Sp + ly * 512 + 8 * X;
        float4 a0 = *(const float4*)Sa;
        float4 a1 = *(const float4*)(Sa + 4);
        float4 a2 = *(const float4*)(Sa + 512);
        float4 a3 = *(const float4*)(Sa + 516);
        const float* Sb = Sa + 262144;
        float4 q0 = *(const float4*)Sb;
        float4 q1 = *(const float4*)(Sb + 4);
        float4 q2 = *(const float4*)(Sb + 512);
        float4 q3 = *(const float4*)(Sb + 516);
        float va[4], vb[4];
        va[0] = (a0.x*cwy + a2.x*wy)*cwx[0] + (a0.y*cwy + a2.y*wy)*wx[0];
        va[1] = (a0.z*cwy + a2.z*wy)*cwx[1] + (a0.w*cwy + a2.w*wy)*wx[1];
        va[2] = (a1.x*cwy + a3.x*wy)*cwx[2] + (a1.y*cwy + a3.y*wy)*wx[2];
        va[3] = (a1.z*cwy + a3.z*wy)*cwx[3] + (a1.w*cwy + a3.w*wy)*wx[3];
        vb[0] = (q0.x*cwy + q2.x*wy)*cwx[0] + (q0.y*cwy + q2.y*wy)*wx[0];
        vb[1] = (q0.z*cwy + q2.z*wy)*cwx[1] + (q0.w*cwy + q2.w*wy)*wx[1];
        vb[2] = (q1.x*cwy + q3.x*wy)*cwx[2] + (q1.y*cwy + q3.y*wy)*wx[2];
        vb[3] = (q1.z*cwy + q3.z*wy)*cwx[3] + (q1.w*cwy + q3.w*wy)*wx[3];
        acc0 += va[0] + va[1] + va[2] + va[3];
        acc1 += vb[0] + vb[1] + vb[2] + vb[3];

        unsigned pr = (pred >> (4 * r)) & 0xF;
        u64 b0 = __ballot(pr & 1);
        u64 b1 = __ballot(pr & 2);
        u64 b2 = __ballot(pr & 4);
        u64 b3 = __ballot(pr & 8);
        u64 ltm = (1ull << lane) - 1ull;
        int pre = __popcll(b0 & ltm) + __popcll(b1 & ltm) +
                  __popcll(b2 & ltm) + __popcll(b3 & ltm);
        int rbase = excl0 + rowb[r] + pre;
        int own = 0;
        #pragma unroll
        for (int j = 0; j < 4; ++j) {
            if (pr & (1u << j)) {
                int row = rbase + own;
                own++;
                int x = 4 * X + j;
                float v0 = va[j], v1 = vb[j];
                float len = sqrtf(v0 * v0 + v1 * v1);
                float n0 = v0 / len, n1 = v1 / len;
                float cy = (float)y + 0.5f, cx = (float)x + 0.5f;
                float rt0 = n1 * 0.5f, rt1 = -n0 * 0.5f;
                ((float2*)out)[row]           = make_float2(cy + rt0, cx + rt1);
                ((float2*)(out + 2*N))[row]   = make_float2(cy - rt0, cx - rt1);
                ((float2*)(out + 4*N))[row]   = make_float2(n0, n1);
                out[6*N + row] = 1.0f;
                ((float2*)(out + 7*N))[row]   = make_float2(cy, cx);
                out[9*N + row] = (float)b;
                out[11*N + row] = (float)((b << 16) + (y << 8) + x);
                // p_rowids written below once N0 is known
            }
        }
    }

    // ---------------- wait for global N0 ------------------------------------
    int guard2 = 0;
    while (__hip_atomic_load(&aux[3], __ATOMIC_ACQUIRE, __HIP_MEMORY_SCOPE_AGENT)
           != NGROUPS) {
        __builtin_amdgcn_s_sleep(2);
        if (++guard2 > (1 << 24)) break;
    }
    int N0 = __hip_atomic_load(&aux[1], __ATOMIC_RELAXED, __HIP_MEMORY_SCOPE_AGENT);

    // parent (this lane's L1 cell) global row — valid whenever any child is active
    int rank1 = __popcll(m1 & ((1ull << lane) - 1ull));
    int prow = N0 + excl1 + rank1;

    // L0 p_rowids (recompute ranks — pure ALU, no loads)
    #pragma unroll
    for (int r = 0; r < 4; ++r) {
        unsigned pr = (pred >> (4 * r)) & 0xF;
        u64 b0 = __ballot(pr & 1);
        u64 b1 = __ballot(pr & 2);
        u64 b2 = __ballot(pr & 4);
        u64 b3 = __ballot(pr & 8);
        u64 ltm = (1ull << lane) - 1ull;
        int pre = __popcll(b0 & ltm) + __popcll(b1 & ltm) +
                  __popcll(b2 & ltm) + __popcll(b3 & ltm);
        int rbase = excl0 + rowb[r] + pre;
        int own = 0;
        #pragma unroll
        for (int j = 0; j < 4; ++j) {
            if (pr & (1u << j)) {
                out[10*N + rbase + own] = (float)prow;
                own++;
            }
        }
    }

    // L1 row for this lane's cell
    if (pred != 0) {
        int row = prow;
        float v0 = acc0 * (1.0f / 16.0f), v1 = acc1 * (1.0f / 16.0f);
        float len = sqrtf(v0 * v0 + v1 * v1);
        float n0 = v0 / len, n1 = v1 / len;
        float cy = ((float)R + 0.5f) * 4.0f, cx = ((float)lane + 0.5f) * 4.0f;
        float rt0 = n1 * 2.0f, rt1 = -n0 * 2.0f;
        ((float2*)out)[row]           = make_float2(cy + rt0, cx + rt1);
        ((float2*)(out + 2*N))[row]   = make_float2(cy - rt0, cx - rt1);
        ((float2*)(out + 4*N))[row]   = make_float2(n0, n1);
        out[6*N + row] = 4.0f;
        ((float2*)(out + 7*N))[row]   = make_float2(cy, cx);
        out[9*N + row] = (float)b;
        out[10*N + row] = (float)row;
        out[11*N + row] = (float)(OFFSET1 + g * 64 + lane);
    }
}

extern "C" void kernel_launch(void* const* d_in, const int* in_sizes, int n_in,
                              void* d_out, int out_size, void* d_ws, size_t ws_size,
                              hipStream_t stream) {
    const float* E = (const float*)d_in[0];   // b_edges (64,1,512,512)
    const float* S = (const float*)d_in[1];   // sobel   (64,2,512,512)
    float* out = (float*)d_out;
    int N = out_size / 12;                    // 8 outputs = 12 floats/row

    u64* state = (u64*)d_ws;                  // NGROUPS u64
    int* aux = (int*)(state + NGROUPS);       // 8 ints: ticket,total0,total1,done

    zero_kernel<<<(NGROUPS + 255) / 256, 256, 0, stream>>>(state, aux);
    fused_kernel<<<512, 512, 0, stream>>>(E, S, state, aux, out, N);
}

// Round 5
// 83.162 us; speedup vs baseline: 7.4903x; 7.4903x over previous
//
#include <hip/hip_runtime.h>
#include <math.h>

// Fixed shapes: b_edges (64,1,512,512) f32, sobel (64,2,512,512) f32
// BASE=256, PY_SIZES=[256,64]
#define OFFSET1 4194304   // lin_id offset of level 1 (=64*256*256)

typedef unsigned long long u64;

// ---- generic align-corners helpers (used only by the no-s0 fallback) ------
__device__ __forceinline__ void ac_coef(int i, int& lo, int& hi, float& w) {
    float p = (float)(i * 511) / 255.0f;
    int l = (int)p;
    lo = l;
    hi = (l + 1 < 511) ? (l + 1) : 511;
    w = p - (float)l;
}
__device__ __forceinline__ float bilin(const float* __restrict__ img,
                                       int ly, int hy, float wy,
                                       int lx, int hx, float wx) {
    float a = img[ly * 512 + lx];
    float b = img[ly * 512 + hx];
    float c = img[hy * 512 + lx];
    float d = img[hy * 512 + hx];
    float rl = a * (1.0f - wy) + c * wy;
    float rh = b * (1.0f - wy) + d * wy;
    return rl * (1.0f - wx) + rh * wx;
}

// spread 16 bits to every 4th bit position of a 64-bit word
__device__ __forceinline__ u64 expand4(unsigned v) {
    u64 x = v & 0xFFFFu;
    x = (x | (x << 24)) & 0x000000FF000000FFull;
    x = (x | (x << 12)) & 0x000F000F000F000Full;
    x = (x | (x << 6))  & 0x0303030303030303ull;
    x = (x | (x << 3))  & 0x1111111111111111ull;
    return x;
}

// ---------------------------------------------------------------------------
// prep: wave-per-group, no LDS, no barriers. Group g = b*64 + R covers output
// rows 4R..4R+3; lane X owns cols 4X..4X+3 (one level-1 cell). 512->256
// align-corners: lo(i)=2i exactly, w(i)=pos(i)-2i (i=255 -> w=1.0, value
// bit-identical to the reference's lo=hi=511 form).
// Produces: mask0 (pixel-ordered predicate bits), counts0[g], counts1[g],
// mask1[g], s1 (pooled sobel), s0 (resized sobel values, float2/pixel).
// ---------------------------------------------------------------------------
__global__ __launch_bounds__(256) void prep_kernel(const float* __restrict__ E,
                                                   const float* __restrict__ S,
                                                   float* __restrict__ s0,
                                                   float* __restrict__ s1,
                                                   u64* __restrict__ mask0,
                                                   u64* __restrict__ mask1,
                                                   int* __restrict__ counts0,
                                                   int* __restrict__ counts1,
                                                   int use_s0) {
    int lane = threadIdx.x & 63;
    int g = blockIdx.x * 4 + (threadIdx.x >> 6);   // 0..4095
    int b = g >> 6, R = g & 63;
    int X = lane;

    float wx[4], cwx[4];
    #pragma unroll
    for (int j = 0; j < 4; ++j) {
        int xi = 4 * X + j;
        wx[j] = (float)(xi * 511) / 255.0f - (float)(8 * X + 2 * j);
        cwx[j] = 1.0f - wx[j];
    }

    unsigned pred = 0;
    int rc = 0;
    float acc0 = 0.0f, acc1 = 0.0f;
    const float* Eb = E + b * 262144;
    const float* Sp = S + (size_t)(b * 2) * 262144;

    #pragma unroll
    for (int r = 0; r < 4; ++r) {
        int y = 4 * R + r, ly = 2 * y;
        float wy = (float)(y * 511) / 255.0f - (float)ly;
        float cwy = 1.0f - wy;

        const float* Ep = Eb + ly * 512 + 8 * X;
        float4 eA = *(const float4*)Ep;
        float4 eB = *(const float4*)(Ep + 4);
        float4 eC = *(const float4*)(Ep + 512);
        float4 eD = *(const float4*)(Ep + 516);
        const float* Sa = Sp + ly * 512 + 8 * X;
        float4 a0 = *(const float4*)Sa;
        float4 a1 = *(const float4*)(Sa + 4);
        float4 a2 = *(const float4*)(Sa + 512);
        float4 a3 = *(const float4*)(Sa + 516);
        const float* Sb = Sa + 262144;
        float4 q0 = *(const float4*)Sb;
        float4 q1 = *(const float4*)(Sb + 4);
        float4 q2 = *(const float4*)(Sb + 512);
        float4 q3 = *(const float4*)(Sb + 516);

        float e0 = (eA.x*cwy + eC.x*wy)*cwx[0] + (eA.y*cwy + eC.y*wy)*wx[0];
        float e1 = (eA.z*cwy + eC.z*wy)*cwx[1] + (eA.w*cwy + eC.w*wy)*wx[1];
        float e2 = (eB.x*cwy + eD.x*wy)*cwx[2] + (eB.y*cwy + eD.y*wy)*wx[2];
        float e3 = (eB.z*cwy + eD.z*wy)*cwx[3] + (eB.w*cwy + eD.w*wy)*wx[3];
        bool p0 = (e0 != 0.0f), p1 = (e1 != 0.0f), p2 = (e2 != 0.0f), p3 = (e3 != 0.0f);
        pred |= (p0?1u:0u) << (4*r+0);
        pred |= (p1?1u:0u) << (4*r+1);
        pred |= (p2?1u:0u) << (4*r+2);
        pred |= (p3?1u:0u) << (4*r+3);
        u64 bl0 = __ballot(p0), bl1 = __ballot(p1), bl2 = __ballot(p2), bl3 = __ballot(p3);
        rc += __popcll(bl0) + __popcll(bl1) + __popcll(bl2) + __popcll(bl3);
        if (lane < 4) {  // 4 lanes emit the row's 4 pixel-ordered mask words
            unsigned w0 = (unsigned)(bl0 >> (16 * lane)) & 0xFFFFu;
            unsigned w1 = (unsigned)(bl1 >> (16 * lane)) & 0xFFFFu;
            unsigned w2 = (unsigned)(bl2 >> (16 * lane)) & 0xFFFFu;
            unsigned w3 = (unsigned)(bl3 >> (16 * lane)) & 0xFFFFu;
            mask0[b * 1024 + y * 4 + lane] =
                expand4(w0) | (expand4(w1) << 1) | (expand4(w2) << 2) | (expand4(w3) << 3);
        }

        float va0 = (a0.x*cwy + a2.x*wy)*cwx[0] + (a0.y*cwy + a2.y*wy)*wx[0];
        float va1 = (a0.z*cwy + a2.z*wy)*cwx[1] + (a0.w*cwy + a2.w*wy)*wx[1];
        float va2 = (a1.x*cwy + a3.x*wy)*cwx[2] + (a1.y*cwy + a3.y*wy)*wx[2];
        float va3 = (a1.z*cwy + a3.z*wy)*cwx[3] + (a1.w*cwy + a3.w*wy)*wx[3];
        float vb0 = (q0.x*cwy + q2.x*wy)*cwx[0] + (q0.y*cwy + q2.y*wy)*wx[0];
        float vb1 = (q0.z*cwy + q2.z*wy)*cwx[1] + (q0.w*cwy + q2.w*wy)*wx[1];
        float vb2 = (q1.x*cwy + q3.x*wy)*cwx[2] + (q1.y*cwy + q3.y*wy)*wx[2];
        float vb3 = (q1.z*cwy + q3.z*wy)*cwx[3] + (q1.w*cwy + q3.w*wy)*wx[3];
        acc0 += va0 + va1 + va2 + va3;
        acc1 += vb0 + vb1 + vb2 + vb3;
        if (use_s0) {
            float4* dst = (float4*)s0 + (size_t)(b * 256 + y) * 128 + 2 * X;
            dst[0] = make_float4(va0, vb0, va1, vb1);
            dst[1] = make_float4(va2, vb2, va3, vb3);
        }
    }

    u64 m1 = __ballot(pred != 0);
    ((float2*)s1)[g * 64 + X] = make_float2(acc0 * (1.0f / 16.0f),
                                            acc1 * (1.0f / 16.0f));
    if (lane == 0) {
        counts0[g] = rc;
        counts1[g] = __popcll(m1);
        mask1[g] = m1;
    }
}

// single-block exclusive scan of counts0[4096] and counts1[4096]
__global__ __launch_bounds__(1024) void scan_kernel(const int* __restrict__ counts0,
                                                    int* __restrict__ offs0,
                                                    const int* __restrict__ counts1,
                                                    int* __restrict__ offs1,
                                                    int* __restrict__ totals) {
    __shared__ int wsum[16];
    int tid = threadIdx.x, lane = tid & 63, wave = tid >> 6;

    int carry = 0;
    for (int base = 0; base < 4096; base += 1024) {
        int v = counts0[base + tid];
        int inc = v;
        #pragma unroll
        for (int d = 1; d < 64; d <<= 1) {
            int t = __shfl_up(inc, (unsigned)d, 64);
            if (lane >= d) inc += t;
        }
        if (lane == 63) wsum[wave] = inc;
        __syncthreads();
        int wbase = 0;
        for (int i = 0; i < wave; ++i) wbase += wsum[i];
        int tot = 0;
        #pragma unroll
        for (int i = 0; i < 16; ++i) tot += wsum[i];
        offs0[base + tid] = carry + wbase + inc - v;
        carry += tot;
        __syncthreads();
    }
    if (tid == 0) totals[0] = carry;

    int carry1 = 0;
    for (int base = 0; base < 4096; base += 1024) {
        int v = counts1[base + tid];
        int inc = v;
        #pragma unroll
        for (int d = 1; d < 64; d <<= 1) {
            int t = __shfl_up(inc, (unsigned)d, 64);
            if (lane >= d) inc += t;
        }
        if (lane == 63) wsum[wave] = inc;
        __syncthreads();
        int wbase = 0;
        for (int i = 0; i < wave; ++i) wbase += wsum[i];
        int tot = 0;
        #pragma unroll
        for (int i = 0; i < 16; ++i) tot += wsum[i];
        offs1[base + tid] = carry1 + wbase + inc - v;
        carry1 += tot;
        __syncthreads();
    }
    if (tid == 0) totals[1] = carry1;
}

__device__ __forceinline__ void write_row(float* __restrict__ out, int N, int row,
                                          float cy, float cx, float s0v, float s1v,
                                          float half, float sz, float imgid,
                                          float prow, float mylin) {
    float len = sqrtf(s0v * s0v + s1v * s1v);
    float n0 = s0v / len, n1 = s1v / len;
    float rt0 = n1 * half, rt1 = -n0 * half;
    ((float2*)out)[row]           = make_float2(cy + rt0, cx + rt1);  // locs_lf
    ((float2*)(out + 2 * N))[row] = make_float2(cy - rt0, cx - rt1);  // locs_rt
    ((float2*)(out + 4 * N))[row] = make_float2(n0, n1);              // norms
    out[6 * N + row] = sz;                                            // sizes
    ((float2*)(out + 7 * N))[row] = make_float2(cy, cx);              // centers
    out[9 * N + row] = imgid;                                         // imgid
    out[10 * N + row] = prow;                                         // p_rowids
    out[11 * N + row] = mylin;                                        // my_lin
}

// level-1 scatter: one wave per (b,Y). Rows [N0, N0+N1).
__global__ __launch_bounds__(1024) void scatter1_kernel(const float* __restrict__ s1,
                                                        const u64* __restrict__ mask1,
                                                        const int* __restrict__ offs1,
                                                        const int* __restrict__ totals,
                                                        int* __restrict__ rank1,
                                                        float* __restrict__ out, int N) {
    int tid = threadIdx.x, lane = tid & 63, wave = tid >> 6;
    int g = blockIdx.x * 16 + wave;              // 0..4095 = b*64 + Y
    u64 m = mask1[g];
    bool pr = (m >> lane) & 1ull;
    if (!pr) return;
    int row = totals[0] + offs1[g] + __popcll(m & ((1ull << lane) - 1ull));
    int q = g * 64 + lane;
    rank1[q] = row;
    float2 sv = ((const float2*)s1)[q];
    int b = g >> 6, Y = g & 63, X = lane;
    float cy = ((float)Y + 0.5f) * 4.0f;
    float cx = ((float)X + 0.5f) * 4.0f;
    write_row(out, N, row, cy, cx, sv.x, sv.y, 2.0f, 4.0f, (float)b,
              (float)row, (float)(OFFSET1 + q));
}

// level-0 scatter: rows [0, N0). Block = (b, R), 4 rows x 256 cols.
__global__ __launch_bounds__(1024) void scatter0_kernel(const float* __restrict__ S,
                                                        const float* __restrict__ s0,
                                                        const u64* __restrict__ mask0,
                                                        const int* __restrict__ offs0,
                                                        const int* __restrict__ rank1,
                                                        float* __restrict__ out, int N,
                                                        int use_s0) {
    int tid = threadIdx.x, lane = tid & 63, wave = tid >> 6;
    int blk = blockIdx.x;                        // b*64 + R
    int b = blk >> 6, R = blk & 63;
    int r = tid >> 8, x = tid & 255;
    int y = 4 * R + r;
    int p = (b << 16) + (y << 8) + x;
    u64 m = mask0[p >> 6];
    __shared__ int wc[16];
    if (lane == 0) wc[wave] = __popcll(m);
    __syncthreads();
    bool pr = (m >> lane) & 1ull;
    if (!pr) return;
    int wbase = 0;
    for (int i = 0; i < wave; ++i) wbase += wc[i];
    int row = offs0[blk] + wbase + __popcll(m & ((1ull << lane) - 1ull));

    float v0, v1;
    if (use_s0) {
        float2 sv = ((const float2*)s0)[(b * 256 + y) * 256 + x];
        v0 = sv.x; v1 = sv.y;
    } else {
        int ly, hy, lx, hx; float wy, wx;
        ac_coef(y, ly, hy, wy);
        ac_coef(x, lx, hx, wx);
        v0 = bilin(S + (size_t)(b * 2 + 0) * 262144, ly, hy, wy, lx, hx, wx);
        v1 = bilin(S + (size_t)(b * 2 + 1) * 262144, ly, hy, wy, lx, hx, wx);
    }
    float cy = (float)y + 0.5f;
    float cx = (float)x + 0.5f;
    int parent = (b << 12) + ((y >> 2) << 6) + (x >> 2);
    write_row(out, N, row, cy, cx, v0, v1, 0.5f, 1.0f, (float)b,
              (float)rank1[parent], (float)p);
}

extern "C" void kernel_launch(void* const* d_in, const int* in_sizes, int n_in,
                              void* d_out, int out_size, void* d_ws, size_t ws_size,
                              hipStream_t stream) {
    const float* E = (const float*)d_in[0];   // b_edges (64,1,512,512)
    const float* S = (const float*)d_in[1];   // sobel   (64,2,512,512)
    float* out = (float*)d_out;
    int N = out_size / 12;                    // 8 outputs = 12 floats/row

    // workspace layout (bytes)
    char* ws = (char*)d_ws;
    int*  rank1   = (int*)ws;                               // 262144 ints = 1 MB
    int*  counts0 = (int*)(ws + 1048576);                   // 4096
    int*  offs0   = counts0 + 4096;
    int*  counts1 = offs0 + 4096;
    int*  offs1   = counts1 + 4096;
    int*  totals  = offs1 + 4096;                           // 2 (+pad)
    u64*  mask0   = (u64*)(ws + 1048576 + 65536 + 64);      // 512 KB
    u64*  mask1   = mask0 + 65536;                          // 32 KB
    float* s1 = (float*)(mask1 + 4096);                     // 524288 floats = 2 MB
    float* s0 = s1 + 524288;                                // 64 MB (float2/px)
    size_t base_bytes = (size_t)((char*)(s1 + 524288) - ws);
    int use_s0 = (ws_size >= base_bytes + 8388608ull * 8ull) ? 1 : 0;

    prep_kernel<<<1024, 256, 0, stream>>>(E, S, (float*)s0, s1,
                                          mask0, mask1, counts0, counts1, use_s0);
    scan_kernel<<<1, 1024, 0, stream>>>(counts0, offs0, counts1, offs1, totals);
    scatter1_kernel<<<256, 1024, 0, stream>>>(s1, mask1, offs1, totals, rank1, out, N);
    scatter0_kernel<<<4096, 1024, 0, stream>>>(S, (const float*)s0, mask0, offs0,
                                               rank1, out, N, use_s0);
}

// Round 6
// 75.864 us; speedup vs baseline: 8.2109x; 1.0962x over previous
//
#include <hip/hip_runtime.h>
#include <math.h>

// Fixed shapes: b_edges (64,1,512,512) f32, sobel (64,2,512,512) f32
// BASE=256, PY_SIZES=[256,64]
// Group g = b*64 + R owns output rows 4R..4R+3 (input rows 8R..8R+7).
// One wave per group; lane X owns output cols 4X..4X+3 == one level-1 cell.
// 512->256 align-corners: pos(i)=i*511/255 (exact f32 product, IEEE div),
// lo(i)=2i, w=pos-2i (i=255 -> w=1.0, bit-identical to the lo=hi=511 form).

typedef unsigned long long u64;
#define OFFSET1 4194304   // lin_id offset of level 1 (=64*256*256)

// ---------------------------------------------------------------------------
// prepE: E-only pass. 16 upfront float4 loads per lane (rows 8R..8R+7, cols
// 8X..8X+7), predicates for the lane's 16 pixels, ballots -> counts + masks.
// ---------------------------------------------------------------------------
__global__ __launch_bounds__(256) void prepE_kernel(const float* __restrict__ E,
                                                    unsigned short* __restrict__ pred16,
                                                    u64* __restrict__ mask1,
                                                    int* __restrict__ counts0,
                                                    int* __restrict__ counts1) {
    int lane = threadIdx.x & 63;
    int g = blockIdx.x * 4 + (threadIdx.x >> 6);     // 0..4095
    int b = g >> 6, R = g & 63;

    const float* Ep = E + b * 262144 + (8 * R) * 512 + 8 * lane;
    float4 L[8], H[8];
    #pragma unroll
    for (int k = 0; k < 8; ++k) {
        L[k] = *(const float4*)(Ep + k * 512);
        H[k] = *(const float4*)(Ep + k * 512 + 4);
    }

    float wx[4], cwx[4];
    #pragma unroll
    for (int j = 0; j < 4; ++j) {
        int xi = 4 * lane + j;
        wx[j] = (float)(xi * 511) / 255.0f - (float)(8 * lane + 2 * j);
        cwx[j] = 1.0f - wx[j];
    }

    unsigned pred = 0;
    int rc = 0;
    #pragma unroll
    for (int r = 0; r < 4; ++r) {
        int y = 4 * R + r;
        float wy = (float)(y * 511) / 255.0f - (float)(2 * y);
        float cwy = 1.0f - wy;
        float4 lo = L[2 * r], loh = H[2 * r];
        float4 hi = L[2 * r + 1], hih = H[2 * r + 1];
        float e0 = (lo.x*cwy + hi.x*wy)*cwx[0] + (lo.y*cwy + hi.y*wy)*wx[0];
        float e1 = (lo.z*cwy + hi.z*wy)*cwx[1] + (lo.w*cwy + hi.w*wy)*wx[1];
        float e2 = (loh.x*cwy + hih.x*wy)*cwx[2] + (loh.y*cwy + hih.y*wy)*wx[2];
        float e3 = (loh.z*cwy + hih.z*wy)*cwx[3] + (loh.w*cwy + hih.w*wy)*wx[3];
        bool p0 = (e0 != 0.0f), p1 = (e1 != 0.0f), p2 = (e2 != 0.0f), p3 = (e3 != 0.0f);
        pred |= (p0?1u:0u) << (4*r+0);
        pred |= (p1?1u:0u) << (4*r+1);
        pred |= (p2?1u:0u) << (4*r+2);
        pred |= (p3?1u:0u) << (4*r+3);
        u64 b0 = __ballot(p0), b1 = __ballot(p1), b2 = __ballot(p2), b3 = __ballot(p3);
        rc += __popcll(b0) + __popcll(b1) + __popcll(b2) + __popcll(b3);
    }
    u64 m1 = __ballot(pred != 0);
    pred16[g * 64 + lane] = (unsigned short)pred;
    if (lane == 0) {
        counts0[g] = rc;
        counts1[g] = __popcll(m1);
        mask1[g] = m1;
    }
}

// single-block exclusive scan of counts0[4096] and counts1[4096]
__global__ __launch_bounds__(1024) void scan_kernel(const int* __restrict__ counts0,
                                                    int* __restrict__ offs0,
                                                    const int* __restrict__ counts1,
                                                    int* __restrict__ offs1,
                                                    int* __restrict__ totals) {
    __shared__ int wsum[16];
    int tid = threadIdx.x, lane = tid & 63, wave = tid >> 6;

    int carry = 0;
    for (int base = 0; base < 4096; base += 1024) {
        int v = counts0[base + tid];
        int inc = v;
        #pragma unroll
        for (int d = 1; d < 64; d <<= 1) {
            int t = __shfl_up(inc, (unsigned)d, 64);
            if (lane >= d) inc += t;
        }
        if (lane == 63) wsum[wave] = inc;
        __syncthreads();
        int wbase = 0;
        for (int i = 0; i < wave; ++i) wbase += wsum[i];
        int tot = 0;
        #pragma unroll
        for (int i = 0; i < 16; ++i) tot += wsum[i];
        offs0[base + tid] = carry + wbase + inc - v;
        carry += tot;
        __syncthreads();
    }
    if (tid == 0) totals[0] = carry;

    int carry1 = 0;
    for (int base = 0; base < 4096; base += 1024) {
        int v = counts1[base + tid];
        int inc = v;
        #pragma unroll
        for (int d = 1; d < 64; d <<= 1) {
            int t = __shfl_up(inc, (unsigned)d, 64);
            if (lane >= d) inc += t;
        }
        if (lane == 63) wsum[wave] = inc;
        __syncthreads();
        int wbase = 0;
        for (int i = 0; i < wave; ++i) wbase += wsum[i];
        int tot = 0;
        #pragma unroll
        for (int i = 0; i < 16; ++i) tot += wsum[i];
        offs1[base + tid] = carry1 + wbase + inc - v;
        carry1 += tot;
        __syncthreads();
    }
    if (tid == 0) totals[1] = carry1;
}

__device__ __forceinline__ void write_row(float* __restrict__ out, int N, int row,
                                          float cy, float cx, float s0v, float s1v,
                                          float half, float sz, float imgid,
                                          float prow, float mylin) {
    float len = sqrtf(s0v * s0v + s1v * s1v);
    float n0 = s0v / len, n1 = s1v / len;
    float rt0 = n1 * half, rt1 = -n0 * half;
    ((float2*)out)[row]           = make_float2(cy + rt0, cx + rt1);  // locs_lf
    ((float2*)(out + 2 * N))[row] = make_float2(cy - rt0, cx - rt1);  // locs_rt
    ((float2*)(out + 4 * N))[row] = make_float2(n0, n1);              // norms
    out[6 * N + row] = sz;                                            // sizes
    ((float2*)(out + 7 * N))[row] = make_float2(cy, cx);              // centers
    out[9 * N + row] = imgid;                                         // imgid
    out[10 * N + row] = prow;                                         // p_rowids
    out[11 * N + row] = mylin;                                        // my_lin
}

// ---------------------------------------------------------------------------
// prepS: S-only pass + ALL output writes. Ranks recomputed in-wave from
// pred16 via ballots; parent row is register-local (lane owns the L1 cell).
// ---------------------------------------------------------------------------
__global__ __launch_bounds__(256) void prepS_kernel(const float* __restrict__ S,
                                                    const unsigned short* __restrict__ pred16,
                                                    const u64* __restrict__ mask1,
                                                    const int* __restrict__ offs0,
                                                    const int* __restrict__ offs1,
                                                    const int* __restrict__ totals,
                                                    float* __restrict__ out, int N) {
    int lane = threadIdx.x & 63;
    int g = blockIdx.x * 4 + (threadIdx.x >> 6);     // 0..4095
    int bimg = g >> 6, R = g & 63;

    u64 m1 = mask1[g];
    if (m1 == 0ull) return;                          // wave-uniform: nothing active
    unsigned pred = pred16[g * 64 + lane];
    int base0 = offs0[g];
    int prow = totals[0] + offs1[g] + __popcll(m1 & ((1ull << lane) - 1ull));

    float wx[4], cwx[4];
    #pragma unroll
    for (int j = 0; j < 4; ++j) {
        int xi = 4 * lane + j;
        wx[j] = (float)(xi * 511) / 255.0f - (float)(8 * lane + 2 * j);
        cwx[j] = 1.0f - wx[j];
    }

    const float* Sa = S + (size_t)(2 * bimg) * 262144 + (8 * R) * 512 + 8 * lane;
    const float* Sq = Sa + 262144;

    float acc0 = 0.0f, acc1 = 0.0f;
    int rc = 0;
    #pragma unroll
    for (int h = 0; h < 2; ++h) {                    // two halves: rows 4h..4h+3
        float4 A[4], Ax[4], Q[4], Qx[4];
        #pragma unroll
        for (int k = 0; k < 4; ++k) {
            const float* pa = Sa + (4 * h + k) * 512;
            A[k]  = *(const float4*)pa;
            Ax[k] = *(const float4*)(pa + 4);
            const float* pq = Sq + (4 * h + k) * 512;
            Q[k]  = *(const float4*)pq;
            Qx[k] = *(const float4*)(pq + 4);
        }
        #pragma unroll
        for (int rr = 0; rr < 2; ++rr) {
            int r = 2 * h + rr;
            int y = 4 * R + r;
            float wy = (float)(y * 511) / 255.0f - (float)(2 * y);
            float cwy = 1.0f - wy;
            float4 lo = A[2*rr], loh = Ax[2*rr], hi = A[2*rr+1], hih = Ax[2*rr+1];
            float4 ql = Q[2*rr], qlh = Qx[2*rr], qh = Q[2*rr+1], qhh = Qx[2*rr+1];
            float va[4], vb[4];
            va[0] = (lo.x*cwy + hi.x*wy)*cwx[0] + (lo.y*cwy + hi.y*wy)*wx[0];
            va[1] = (lo.z*cwy + hi.z*wy)*cwx[1] + (lo.w*cwy + hi.w*wy)*wx[1];
            va[2] = (loh.x*cwy + hih.x*wy)*cwx[2] + (loh.y*cwy + hih.y*wy)*wx[2];
            va[3] = (loh.z*cwy + hih.z*wy)*cwx[3] + (loh.w*cwy + hih.w*wy)*wx[3];
            vb[0] = (ql.x*cwy + qh.x*wy)*cwx[0] + (ql.y*cwy + qh.y*wy)*wx[0];
            vb[1] = (ql.z*cwy + qh.z*wy)*cwx[1] + (ql.w*cwy + qh.w*wy)*wx[1];
            vb[2] = (qlh.x*cwy + qhh.x*wy)*cwx[2] + (qlh.y*cwy + qhh.y*wy)*wx[2];
            vb[3] = (qlh.z*cwy + qhh.z*wy)*cwx[3] + (qlh.w*cwy + qhh.w*wy)*wx[3];
            acc0 += va[0] + va[1] + va[2] + va[3];
            acc1 += vb[0] + vb[1] + vb[2] + vb[3];

            unsigned pr = (pred >> (4 * r)) & 0xF;
            u64 b0 = __ballot(pr & 1);
            u64 b1 = __ballot(pr & 2);
            u64 b2 = __ballot(pr & 4);
            u64 b3 = __ballot(pr & 8);
            u64 ltm = (1ull << lane) - 1ull;
            int pre = __popcll(b0 & ltm) + __popcll(b1 & ltm) +
                      __popcll(b2 & ltm) + __popcll(b3 & ltm);
            int rbase = base0 + rc + pre;
            int own = 0;
            #pragma unroll
            for (int j = 0; j < 4; ++j) {
                if (pr & (1u << j)) {
                    int row = rbase + own;
                    own++;
                    int x = 4 * lane + j;
                    float cy = (float)y + 0.5f, cx = (float)x + 0.5f;
                    write_row(out, N, row, cy, cx, va[j], vb[j], 0.5f, 1.0f,
                              (float)bimg, (float)prow,
                              (float)((bimg << 16) + (y << 8) + x));
                }
            }
            rc += __popcll(b0) + __popcll(b1) + __popcll(b2) + __popcll(b3);
        }
    }

    // level-1 row for this lane's cell
    if (pred != 0) {
        float v0 = acc0 * (1.0f / 16.0f), v1 = acc1 * (1.0f / 16.0f);
        float cy = ((float)R + 0.5f) * 4.0f, cx = ((float)lane + 0.5f) * 4.0f;
        write_row(out, N, prow, cy, cx, v0, v1, 2.0f, 4.0f, (float)bimg,
                  (float)prow, (float)(OFFSET1 + g * 64 + lane));
    }
}

extern "C" void kernel_launch(void* const* d_in, const int* in_sizes, int n_in,
                              void* d_out, int out_size, void* d_ws, size_t ws_size,
                              hipStream_t stream) {
    const float* E = (const float*)d_in[0];   // b_edges (64,1,512,512)
    const float* S = (const float*)d_in[1];   // sobel   (64,2,512,512)
    float* out = (float*)d_out;
    int N = out_size / 12;                    // 8 outputs = 12 floats/row

    // workspace layout (byte offsets); ~622 KB total, all written before read
    char* ws = (char*)d_ws;
    int* counts0 = (int*)(ws + 0);            // 4096 ints
    int* offs0   = (int*)(ws + 16384);        // 4096
    int* counts1 = (int*)(ws + 32768);        // 4096
    int* offs1   = (int*)(ws + 49152);        // 4096
    int* totals  = (int*)(ws + 65536);        // 2
    u64* mask1   = (u64*)(ws + 65600);        // 4096 u64 = 32 KB (8B aligned)
    unsigned short* pred16 = (unsigned short*)(ws + 98368);  // 262144 ushort = 512 KB

    prepE_kernel<<<1024, 256, 0, stream>>>(E, pred16, mask1, counts0, counts1);
    scan_kernel<<<1, 1024, 0, stream>>>(counts0, offs0, counts1, offs1, totals);
    prepS_kernel<<<1024, 256, 0, stream>>>(S, pred16, mask1, offs0, offs1,
                                           totals, out, N);
}